// Round 6
// baseline (232.919 us; speedup 1.0000x reference)
//
#include <hip/hip_runtime.h>

// OmniAttention mixed-mask flash attention, MI355X gfx950.
// B=12, H=8, S=1024, D=64. OUTPUT IS FLOAT32 (R5 diagnostic: short writes
// read back as fp32 denormals -> all-zero; fp32 store is the fix).
// Input float dtype (bf16 vs fp32) runtime-detected (flags in d_ws).
// Block = 256 threads (4 waves) = one (b, h, 64-row q-tile); 64-col kv tiles.
// MFMA 16x16x32 bf16. Verified layouts (learn_hip m89/m91/m97/m120):
//   C/D: col = lane&15, row = (lane>>4)*4 + reg
//   A  : m = lane&15,  k = (lane>>4)*8 + j
//   B  : n = lane&15,  k = (lane>>4)*8 + j

typedef __attribute__((ext_vector_type(8))) short short8;
typedef __attribute__((ext_vector_type(4))) float floatx4;

#define S_LEN 1024
#define D_DIM 64
#define H_NUM 8
#define B_NUM 12
#define BT2I_CONST 4
#define BLM_CONST 4
#define NUM_CLIP_P3 579   // NUM_CLIP_VIT_FEAT + 3

__device__ __forceinline__ float bf2f(short s) {
    unsigned int u = ((unsigned int)(unsigned short)s) << 16;
    return __builtin_bit_cast(float, u);
}
__device__ __forceinline__ short f2bf(float f) {
    unsigned int u = __builtin_bit_cast(unsigned int, f);
    unsigned int r = (u + 0x7fffu + ((u >> 16) & 1u)) >> 16;
    return (short)(unsigned short)r;
}
// bf16 * 0.125 is exact (exponent shift only)
__device__ __forceinline__ short scale_bf(short x) {
    float f = bf2f(x) * 0.125f;
    return (short)(unsigned short)(__builtin_bit_cast(unsigned int, f) >> 16);
}

// flags[0]: 1 if q/k/v bf16-packed, 0 if fp32.
__global__ void detect_layout(const unsigned int* __restrict__ q,
                              int* __restrict__ flags) {
    int l = threadIdx.x & 63;
    unsigned int w = q[l];
    unsigned int e = (w >> 7) & 0xffu;   // bf16 exponent field of low short
    bool sane = (e >= 100u && e <= 140u);
    unsigned long long m = __ballot(sane);
    if (l == 0) flags[0] = (__popcll(m) > 32) ? 1 : 0;
}

__global__ __launch_bounds__(256)
void omni_attn_kernel(const void* __restrict__ Qv, const void* __restrict__ Kv,
                      const void* __restrict__ Vv, const int* __restrict__ pad_ends,
                      const int* __restrict__ fstarts, const int* __restrict__ fends,
                      const int* __restrict__ flags, float* __restrict__ Out) {
    __shared__ short Ks[64][72];      // [kv][d], +8 pad
    __shared__ short Vts[64][72];     // [d][kv], +8 pad (V transposed)
    __shared__ short Ps[4][16][72];   // per-wave P round-trip buffer
    __shared__ int   padv[64];        // per-kv-column pad bit

    const int qt = blockIdx.x;   // 0..15 (q tile of 64)
    const int h  = blockIdx.y;
    const int b  = blockIdx.z;
    const int t  = threadIdx.x;
    const int wq = t >> 6;       // wave 0..3
    const int l  = t & 63;
    const int lane16 = l & 15;
    const int quad = l >> 4;

    const int is_bf16 = flags[0];
    const int cls = (b < BT2I_CONST) ? 0 : ((b < BT2I_CONST + BLM_CONST) ? 1 : 2);

    const int bh = b * H_NUM + h;
    const long long base = (long long)bh * S_LEN * D_DIM;
    const short* Qb16 = (const short*)Qv + base;
    const short* Kb16 = (const short*)Kv + base;
    const short* Vb16 = (const short*)Vv + base;
    const float* Qbf  = (const float*)Qv + base;
    const float* Kbf  = (const float*)Kv + base;
    const float* Vbf  = (const float*)Vv + base;

    const int qbase = qt * 64 + wq * 16;

    // ---- Q fragments (A-layout), pre-scaled by 1/sqrt(D)=0.125 ----
    short8 aq0, aq1;
    if (is_bf16) {
        const short8* qp = (const short8*)(Qb16 + (qbase + lane16) * D_DIM + quad * 8);
        short8 r0 = qp[0];   // d = quad*8 + j
        short8 r1 = qp[4];   // d = 32 + quad*8 + j
        #pragma unroll
        for (int j = 0; j < 8; ++j) { aq0[j] = scale_bf(r0[j]); aq1[j] = scale_bf(r1[j]); }
    } else {
        const floatx4* qp = (const floatx4*)(Qbf + (qbase + lane16) * D_DIM + quad * 8);
        floatx4 f0 = qp[0], f1 = qp[1], f2 = qp[8], f3 = qp[9];
        #pragma unroll
        for (int j = 0; j < 4; ++j) {
            aq0[j]     = f2bf(f0[j] * 0.125f);
            aq0[4 + j] = f2bf(f1[j] * 0.125f);
            aq1[j]     = f2bf(f2[j] * 0.125f);
            aq1[4 + j] = f2bf(f3[j] * 0.125f);
        }
    }

    // per-lane row constants (4 C-rows per lane)
    int qg[4], fs[4], fe[4];
    #pragma unroll
    for (int r = 0; r < 4; ++r) {
        qg[r] = qbase + quad * 4 + r;
        fs[r] = fstarts[qg[r]];
        fe[r] = fends[qg[r]];
    }

    floatx4 Oc[4];
    #pragma unroll
    for (int c = 0; c < 4; ++c) Oc[c] = (floatx4){0.f, 0.f, 0.f, 0.f};
    float m_i[4] = {-1e30f, -1e30f, -1e30f, -1e30f};
    float l_i[4] = {0.f, 0.f, 0.f, 0.f};

    for (int kt = 0; kt < S_LEN / 64; ++kt) {
        const int kvbase = kt * 64;
        __syncthreads();   // protect LDS from previous iteration's readers

        // ---- stage K [kv][d], V^T [d][kv], pad bits ----
        {
            const int kvr = t >> 2;   // 0..63
            const int seg = t & 3;    // 0..3
            if (is_bf16) {
                const short8* gk = (const short8*)(Kb16 + (kvbase + kvr) * D_DIM);
                *(short8*)&Ks[kvr][seg * 8]       = gk[seg];
                *(short8*)&Ks[kvr][(seg + 4) * 8] = gk[seg + 4];
                const short8* gv = (const short8*)(Vb16 + (kvbase + kvr) * D_DIM);
                short8 v0 = gv[seg], v1 = gv[seg + 4];
                #pragma unroll
                for (int j = 0; j < 8; ++j) {
                    Vts[seg * 8 + j][kvr]      = v0[j];
                    Vts[32 + seg * 8 + j][kvr] = v1[j];
                }
            } else {
                const floatx4* gk = (const floatx4*)(Kbf + (kvbase + kvr) * D_DIM);
                floatx4 k0 = gk[seg * 2], k1 = gk[seg * 2 + 1];
                floatx4 k2 = gk[8 + seg * 2], k3 = gk[8 + seg * 2 + 1];
                #pragma unroll
                for (int j = 0; j < 4; ++j) {
                    Ks[kvr][seg * 8 + j]          = f2bf(k0[j]);
                    Ks[kvr][seg * 8 + 4 + j]      = f2bf(k1[j]);
                    Ks[kvr][32 + seg * 8 + j]     = f2bf(k2[j]);
                    Ks[kvr][32 + seg * 8 + 4 + j] = f2bf(k3[j]);
                }
                const floatx4* gv = (const floatx4*)(Vbf + (kvbase + kvr) * D_DIM);
                floatx4 v0 = gv[seg * 2], v1 = gv[seg * 2 + 1];
                floatx4 v2 = gv[8 + seg * 2], v3 = gv[8 + seg * 2 + 1];
                #pragma unroll
                for (int j = 0; j < 4; ++j) {
                    Vts[seg * 8 + j][kvr]          = f2bf(v0[j]);
                    Vts[seg * 8 + 4 + j][kvr]      = f2bf(v1[j]);
                    Vts[32 + seg * 8 + j][kvr]     = f2bf(v2[j]);
                    Vts[32 + seg * 8 + 4 + j][kvr] = f2bf(v3[j]);
                }
            }
            if (t < 64) {
                int kg = kvbase + t;
                padv[t] = (kg < pad_ends[b * S_LEN + kg]) ? 1 : 0;
            }
        }
        __syncthreads();

        // ---- QK^T: scores 16q x 64kv per wave ----
        floatx4 sc[4];
        #pragma unroll
        for (int f = 0; f < 4; ++f) {
            short8 b0 = *(const short8*)&Ks[f * 16 + lane16][quad * 8];
            short8 b1 = *(const short8*)&Ks[f * 16 + lane16][32 + quad * 8];
            floatx4 c = (floatx4){0.f, 0.f, 0.f, 0.f};
            c = __builtin_amdgcn_mfma_f32_16x16x32_bf16(aq0, b0, c, 0, 0, 0);
            c = __builtin_amdgcn_mfma_f32_16x16x32_bf16(aq1, b1, c, 0, 0, 0);
            sc[f] = c;
        }

        // ---- mask (reference semantics; masked = -1e30, never skipped) ----
        int col[4], cpad[4];
        #pragma unroll
        for (int f = 0; f < 4; ++f) {
            col[f] = kvbase + f * 16 + lane16;
            cpad[f] = padv[f * 16 + lane16];
        }
        if (cls == 0) {
            #pragma unroll
            for (int r = 0; r < 4; ++r) {
                const int q = qg[r];
                #pragma unroll
                for (int f = 0; f < 4; ++f) {
                    const int k = col[f];
                    bool causal = (!cpad[f]) && (q >= k);
                    bool full   = (k >= fs[r]) && (k < fe[r]);
                    bool m      = (q == k) != (causal || full);   // XOR
                    sc[f][r] = m ? sc[f][r] : -1e30f;
                }
            }
        } else if (cls == 1) {
            #pragma unroll
            for (int r = 0; r < 4; ++r) {
                const int q = qg[r];
                #pragma unroll
                for (int f = 0; f < 4; ++f)
                    sc[f][r] = (q >= col[f]) ? sc[f][r] : -1e30f;
            }
        } else {
            #pragma unroll
            for (int r = 0; r < 4; ++r) {
                const int q = qg[r];
                #pragma unroll
                for (int f = 0; f < 4; ++f) {
                    bool m = (q >= col[f]) || (col[f] <= NUM_CLIP_P3);
                    sc[f][r] = m ? sc[f][r] : -1e30f;
                }
            }
        }

        // ---- online softmax (row lives across the 16 lanes sharing quad) ----
        #pragma unroll
        for (int r = 0; r < 4; ++r) {
            float rmax = fmaxf(fmaxf(sc[0][r], sc[1][r]), fmaxf(sc[2][r], sc[3][r]));
            #pragma unroll
            for (int off = 1; off < 16; off <<= 1)
                rmax = fmaxf(rmax, __shfl_xor(rmax, off, 64));
            float mnew = fmaxf(m_i[r], rmax);
            float alpha = __expf(m_i[r] - mnew);
            m_i[r] = mnew;
            float psum = 0.f;
            #pragma unroll
            for (int f = 0; f < 4; ++f) {
                float p = __expf(sc[f][r] - mnew);
                sc[f][r] = p;
                psum += p;
            }
            #pragma unroll
            for (int off = 1; off < 16; off <<= 1)
                psum += __shfl_xor(psum, off, 64);
            l_i[r] = l_i[r] * alpha + psum;
            Oc[0][r] *= alpha; Oc[1][r] *= alpha; Oc[2][r] *= alpha; Oc[3][r] *= alpha;
        }

        // ---- P: C-layout -> LDS -> A-layout (bf16), barrier-fenced ----
        #pragma unroll
        for (int r = 0; r < 4; ++r)
            #pragma unroll
            for (int f = 0; f < 4; ++f)
                Ps[wq][quad * 4 + r][f * 16 + lane16] = f2bf(sc[f][r]);
        __syncthreads();   // hard fence: all P writes visible before reads

        short8 a0 = *(const short8*)&Ps[wq][lane16][quad * 8];
        short8 a1 = *(const short8*)&Ps[wq][lane16][32 + quad * 8];
        #pragma unroll
        for (int c = 0; c < 4; ++c) {
            short8 b0 = *(const short8*)&Vts[c * 16 + lane16][quad * 8];
            short8 b1 = *(const short8*)&Vts[c * 16 + lane16][32 + quad * 8];
            Oc[c] = __builtin_amdgcn_mfma_f32_16x16x32_bf16(a0, b0, Oc[c], 0, 0, 0);
            Oc[c] = __builtin_amdgcn_mfma_f32_16x16x32_bf16(a1, b1, Oc[c], 0, 0, 0);
        }
    }

    // ---- epilogue: O / l, store FLOAT32 ----
    float* ob = Out + ((long long)bh * S_LEN + qbase) * D_DIM;
    #pragma unroll
    for (int r = 0; r < 4; ++r) {
        float inv = 1.0f / l_i[r];
        #pragma unroll
        for (int c = 0; c < 4; ++c)
            ob[(quad * 4 + r) * D_DIM + c * 16 + lane16] = Oc[c][r] * inv;
    }
}

extern "C" void kernel_launch(void* const* d_in, const int* in_sizes, int n_in,
                              void* d_out, int out_size, void* d_ws, size_t ws_size,
                              hipStream_t stream) {
    const void* Q = d_in[0];
    const void* K = d_in[1];
    const void* V = d_in[2];
    const int* pad_ends = (const int*)d_in[3];
    const int* fstarts  = (const int*)d_in[4];
    const int* fends    = (const int*)d_in[5];
    float* Out = (float*)d_out;
    int* flags = (int*)d_ws;

    detect_layout<<<1, 64, 0, stream>>>((const unsigned int*)Q, flags);

    dim3 grid(S_LEN / 64, H_NUM, B_NUM);
    dim3 block(256);
    omni_attn_kernel<<<grid, block, 0, stream>>>(Q, K, V, pad_ends, fstarts, fends,
                                                 flags, Out);
}

// Round 7
// 224.561 us; speedup vs baseline: 1.0372x; 1.0372x over previous
//
#include <hip/hip_runtime.h>

// OmniAttention mixed-mask flash attention, MI355X gfx950.
// B=12, H=8, S=1024, D=64. Inputs fp32-or-bf16 (runtime-detected), OUTPUT fp32.
// R7: preprocess pass converts K->bf16 and V->bf16-TRANSPOSED into d_ws once,
// so the main kernel stages tiles with pure b128 copies (no per-tile cvt, no
// LDS scatter -> kills the 1.8e7 bank conflicts and ~200 VALU/lane/tile of
// R6). 1-D grid swizzled so all q-tiles of one (b,h) share an XCD (L2 reuse).
// Fallback to the R6-style kernel if ws_size is too small.
// MFMA 16x16x32 bf16. Verified layouts (learn_hip m89/m91/m97/m120):
//   C/D: col = lane&15, row = (lane>>4)*4 + reg
//   A  : m = lane&15,  k = (lane>>4)*8 + j
//   B  : n = lane&15,  k = (lane>>4)*8 + j

typedef __attribute__((ext_vector_type(8))) short short8;
typedef __attribute__((ext_vector_type(4))) float floatx4;

#define S_LEN 1024
#define D_DIM 64
#define H_NUM 8
#define B_NUM 12
#define BT2I_CONST 4
#define BLM_CONST 4
#define NUM_CLIP_P3 579   // NUM_CLIP_VIT_FEAT + 3
#define KV_ELEMS (B_NUM * H_NUM * S_LEN * D_DIM)   // 6291456 per tensor

__device__ __forceinline__ float bf2f(short s) {
    unsigned int u = ((unsigned int)(unsigned short)s) << 16;
    return __builtin_bit_cast(float, u);
}
__device__ __forceinline__ short f2bf(float f) {
    unsigned int u = __builtin_bit_cast(unsigned int, f);
    unsigned int r = (u + 0x7fffu + ((u >> 16) & 1u)) >> 16;
    return (short)(unsigned short)r;
}
__device__ __forceinline__ short scale_bf(short x) {   // *0.125 exact
    float f = bf2f(x) * 0.125f;
    return (short)(unsigned short)(__builtin_bit_cast(unsigned int, f) >> 16);
}

// flags[0]: 1 if q/k/v bf16-packed, 0 if fp32.
__global__ void detect_layout(const unsigned int* __restrict__ q,
                              int* __restrict__ flags) {
    int l = threadIdx.x & 63;
    unsigned int w = q[l];
    unsigned int e = (w >> 7) & 0xffu;
    bool sane = (e >= 100u && e <= 140u);
    unsigned long long m = __ballot(sane);
    if (l == 0) flags[0] = (__popcll(m) > 32) ? 1 : 0;
}

// ---- preprocess: z=0 -> K straight convert; z=1 -> V convert+transpose ----
// grid (16 kv-tiles, 96 bh, 2), block 256.
__global__ __launch_bounds__(256)
void preprocess_kv(const void* __restrict__ Kv, const void* __restrict__ Vv,
                   const int* __restrict__ flags,
                   short* __restrict__ Kw, short* __restrict__ Vtw) {
    __shared__ short Ls[64][72];
    const int tile = blockIdx.x;
    const int bh   = blockIdx.y;
    const int t    = threadIdx.x;
    const int is_bf16 = flags[0];
    const int kvbase = tile * 64;
    const long long base = (long long)bh * S_LEN * D_DIM;
    const int row = t >> 2;
    const int c0  = (t & 3) * 16;

    if (blockIdx.z == 0) {
        long long src = base + (long long)(kvbase + row) * D_DIM + c0;
        short tmp[16];
        if (is_bf16) {
            const short* p = (const short*)Kv + src;
            #pragma unroll
            for (int j = 0; j < 16; ++j) tmp[j] = p[j];
        } else {
            const float* p = (const float*)Kv + src;
            #pragma unroll
            for (int j = 0; j < 16; ++j) tmp[j] = f2bf(p[j]);
        }
        *(short8*)(Kw + src)     = *(short8*)&tmp[0];
        *(short8*)(Kw + src + 8) = *(short8*)&tmp[8];
    } else {
        long long src = base + (long long)(kvbase + row) * D_DIM + c0;
        if (is_bf16) {
            const short* p = (const short*)Vv + src;
            #pragma unroll
            for (int j = 0; j < 16; ++j) Ls[row][c0 + j] = p[j];
        } else {
            const float* p = (const float*)Vv + src;
            #pragma unroll
            for (int j = 0; j < 16; ++j) Ls[row][c0 + j] = f2bf(p[j]);
        }
        __syncthreads();
        const int d  = t >> 2;        // output row (d)
        const int k0 = (t & 3) * 16;  // kv segment within tile
        short tmp[16];
        #pragma unroll
        for (int j = 0; j < 16; ++j) tmp[j] = Ls[k0 + j][d];
        long long dst = (long long)bh * D_DIM * S_LEN + (long long)d * S_LEN + kvbase + k0;
        *(short8*)(Vtw + dst)     = *(short8*)&tmp[0];
        *(short8*)(Vtw + dst + 8) = *(short8*)&tmp[8];
    }
}

// ---- main kernel: 1-D grid, lid = h + 8*(qt + 16*b) ----
__global__ __launch_bounds__(256)
void omni_attn_main(const void* __restrict__ Qv, const int* __restrict__ pad_ends,
                    const int* __restrict__ fstarts, const int* __restrict__ fends,
                    const int* __restrict__ flags,
                    const short* __restrict__ Kw, const short* __restrict__ Vtw,
                    float* __restrict__ Out) {
    __shared__ short Ks[64][72];
    __shared__ short Vts[64][72];
    __shared__ short Ps[4][16][72];
    __shared__ int   padv[64];

    const int lid = blockIdx.x;
    const int h  = lid & 7;
    const int qt = (lid >> 3) & 15;
    const int b  = lid >> 7;
    const int t  = threadIdx.x;
    const int wq = t >> 6;
    const int l  = t & 63;
    const int lane16 = l & 15;
    const int quad = l >> 4;

    const int is_bf16 = flags[0];
    const int cls = (b < BT2I_CONST) ? 0 : ((b < BT2I_CONST + BLM_CONST) ? 1 : 2);

    const int bh = b * H_NUM + h;
    const long long base = (long long)bh * S_LEN * D_DIM;
    const int qbase = qt * 64 + wq * 16;

    // ---- Q fragments (A-layout), pre-scaled by 1/sqrt(D)=0.125 ----
    short8 aq0, aq1;
    if (is_bf16) {
        const short8* qp = (const short8*)((const short*)Qv + base
                                           + (qbase + lane16) * D_DIM + quad * 8);
        short8 r0 = qp[0], r1 = qp[4];
        #pragma unroll
        for (int j = 0; j < 8; ++j) { aq0[j] = scale_bf(r0[j]); aq1[j] = scale_bf(r1[j]); }
    } else {
        const floatx4* qp = (const floatx4*)((const float*)Qv + base
                                             + (qbase + lane16) * D_DIM + quad * 8);
        floatx4 f0 = qp[0], f1 = qp[1], f2 = qp[8], f3 = qp[9];
        #pragma unroll
        for (int j = 0; j < 4; ++j) {
            aq0[j]     = f2bf(f0[j] * 0.125f);
            aq0[4 + j] = f2bf(f1[j] * 0.125f);
            aq1[j]     = f2bf(f2[j] * 0.125f);
            aq1[4 + j] = f2bf(f3[j] * 0.125f);
        }
    }

    int qg[4], fs[4], fe[4];
    #pragma unroll
    for (int r = 0; r < 4; ++r) {
        qg[r] = qbase + quad * 4 + r;
        fs[r] = fstarts[qg[r]];
        fe[r] = fends[qg[r]];
    }

    floatx4 Oc[4];
    #pragma unroll
    for (int c = 0; c < 4; ++c) Oc[c] = (floatx4){0.f, 0.f, 0.f, 0.f};
    float m_i[4] = {-1e30f, -1e30f, -1e30f, -1e30f};
    float l_i[4] = {0.f, 0.f, 0.f, 0.f};

    const short* Kbh  = Kw  + base;                       // [kv][d] bf16
    const short* Vtbh = Vtw + (long long)bh * D_DIM * S_LEN;  // [d][kv] bf16

    for (int kt = 0; kt < S_LEN / 64; ++kt) {
        const int kvbase = kt * 64;
        __syncthreads();

        // ---- stage K tile + V^T tile: pure b128 copies ----
        {
            const int r0 = t >> 2;    // K: kv row / Vt: d row
            const int s  = t & 3;
            const short8* gk = (const short8*)(Kbh + (long long)(kvbase + r0) * D_DIM);
            *(short8*)&Ks[r0][s * 8]       = gk[s];
            *(short8*)&Ks[r0][(s + 4) * 8] = gk[s + 4];
            const short8* gv = (const short8*)(Vtbh + (long long)r0 * S_LEN + kvbase);
            *(short8*)&Vts[r0][s * 8]       = gv[s];
            *(short8*)&Vts[r0][(s + 4) * 8] = gv[s + 4];
            if (t < 64) {
                int kg = kvbase + t;
                padv[t] = (kg < pad_ends[b * S_LEN + kg]) ? 1 : 0;
            }
        }
        __syncthreads();

        // ---- QK^T: 16q x 64kv per wave ----
        floatx4 sc[4];
        #pragma unroll
        for (int f = 0; f < 4; ++f) {
            short8 b0 = *(const short8*)&Ks[f * 16 + lane16][quad * 8];
            short8 b1 = *(const short8*)&Ks[f * 16 + lane16][32 + quad * 8];
            floatx4 c = (floatx4){0.f, 0.f, 0.f, 0.f};
            c = __builtin_amdgcn_mfma_f32_16x16x32_bf16(aq0, b0, c, 0, 0, 0);
            c = __builtin_amdgcn_mfma_f32_16x16x32_bf16(aq1, b1, c, 0, 0, 0);
            sc[f] = c;
        }

        // ---- mask ----
        int col[4], cpad[4];
        #pragma unroll
        for (int f = 0; f < 4; ++f) {
            col[f] = kvbase + f * 16 + lane16;
            cpad[f] = padv[f * 16 + lane16];
        }
        if (cls == 0) {
            #pragma unroll
            for (int r = 0; r < 4; ++r) {
                const int q = qg[r];
                #pragma unroll
                for (int f = 0; f < 4; ++f) {
                    const int k = col[f];
                    bool causal = (!cpad[f]) && (q >= k);
                    bool full   = (k >= fs[r]) && (k < fe[r]);
                    bool m      = (q == k) != (causal || full);
                    sc[f][r] = m ? sc[f][r] : -1e30f;
                }
            }
        } else if (cls == 1) {
            #pragma unroll
            for (int r = 0; r < 4; ++r) {
                const int q = qg[r];
                #pragma unroll
                for (int f = 0; f < 4; ++f)
                    sc[f][r] = (q >= col[f]) ? sc[f][r] : -1e30f;
            }
        } else {
            #pragma unroll
            for (int r = 0; r < 4; ++r) {
                const int q = qg[r];
                #pragma unroll
                for (int f = 0; f < 4; ++f) {
                    bool m = (q >= col[f]) || (col[f] <= NUM_CLIP_P3);
                    sc[f][r] = m ? sc[f][r] : -1e30f;
                }
            }
        }

        // ---- online softmax ----
        #pragma unroll
        for (int r = 0; r < 4; ++r) {
            float rmax = fmaxf(fmaxf(sc[0][r], sc[1][r]), fmaxf(sc[2][r], sc[3][r]));
            #pragma unroll
            for (int off = 1; off < 16; off <<= 1)
                rmax = fmaxf(rmax, __shfl_xor(rmax, off, 64));
            float mnew = fmaxf(m_i[r], rmax);
            float alpha = __expf(m_i[r] - mnew);
            m_i[r] = mnew;
            float psum = 0.f;
            #pragma unroll
            for (int f = 0; f < 4; ++f) {
                float p = __expf(sc[f][r] - mnew);
                sc[f][r] = p;
                psum += p;
            }
            #pragma unroll
            for (int off = 1; off < 16; off <<= 1)
                psum += __shfl_xor(psum, off, 64);
            l_i[r] = l_i[r] * alpha + psum;
            Oc[0][r] *= alpha; Oc[1][r] *= alpha; Oc[2][r] *= alpha; Oc[3][r] *= alpha;
        }

        // ---- P: C-layout -> LDS -> A-layout ----
        #pragma unroll
        for (int r = 0; r < 4; ++r)
            #pragma unroll
            for (int f = 0; f < 4; ++f)
                Ps[wq][quad * 4 + r][f * 16 + lane16] = f2bf(sc[f][r]);
        __syncthreads();

        short8 a0 = *(const short8*)&Ps[wq][lane16][quad * 8];
        short8 a1 = *(const short8*)&Ps[wq][lane16][32 + quad * 8];
        #pragma unroll
        for (int c = 0; c < 4; ++c) {
            short8 b0 = *(const short8*)&Vts[c * 16 + lane16][quad * 8];
            short8 b1 = *(const short8*)&Vts[c * 16 + lane16][32 + quad * 8];
            Oc[c] = __builtin_amdgcn_mfma_f32_16x16x32_bf16(a0, b0, Oc[c], 0, 0, 0);
            Oc[c] = __builtin_amdgcn_mfma_f32_16x16x32_bf16(a1, b1, Oc[c], 0, 0, 0);
        }
    }

    float* ob = Out + ((long long)bh * S_LEN + qbase) * D_DIM;
    #pragma unroll
    for (int r = 0; r < 4; ++r) {
        float inv = 1.0f / l_i[r];
        #pragma unroll
        for (int c = 0; c < 4; ++c)
            ob[(quad * 4 + r) * D_DIM + c * 16 + lane16] = Oc[c][r] * inv;
    }
}

// ---- fallback (R6, passing): used only if ws_size too small ----
__global__ __launch_bounds__(256)
void omni_attn_fallback(const void* __restrict__ Qv, const void* __restrict__ Kv,
                        const void* __restrict__ Vv, const int* __restrict__ pad_ends,
                        const int* __restrict__ fstarts, const int* __restrict__ fends,
                        const int* __restrict__ flags, float* __restrict__ Out) {
    __shared__ short Ks[64][72];
    __shared__ short Vts[64][72];
    __shared__ short Ps[4][16][72];
    __shared__ int   padv[64];

    const int qt = blockIdx.x, h = blockIdx.y, b = blockIdx.z;
    const int t = threadIdx.x, wq = t >> 6, l = t & 63;
    const int lane16 = l & 15, quad = l >> 4;
    const int is_bf16 = flags[0];
    const int cls = (b < BT2I_CONST) ? 0 : ((b < BT2I_CONST + BLM_CONST) ? 1 : 2);
    const int bh = b * H_NUM + h;
    const long long base = (long long)bh * S_LEN * D_DIM;
    const short* Kb16 = (const short*)Kv + base;
    const short* Vb16 = (const short*)Vv + base;
    const float* Kbf  = (const float*)Kv + base;
    const float* Vbf  = (const float*)Vv + base;
    const int qbase = qt * 64 + wq * 16;

    short8 aq0, aq1;
    if (is_bf16) {
        const short8* qp = (const short8*)((const short*)Qv + base + (qbase + lane16) * D_DIM + quad * 8);
        short8 r0 = qp[0], r1 = qp[4];
        #pragma unroll
        for (int j = 0; j < 8; ++j) { aq0[j] = scale_bf(r0[j]); aq1[j] = scale_bf(r1[j]); }
    } else {
        const floatx4* qp = (const floatx4*)((const float*)Qv + base + (qbase + lane16) * D_DIM + quad * 8);
        floatx4 f0 = qp[0], f1 = qp[1], f2 = qp[8], f3 = qp[9];
        #pragma unroll
        for (int j = 0; j < 4; ++j) {
            aq0[j] = f2bf(f0[j] * 0.125f); aq0[4 + j] = f2bf(f1[j] * 0.125f);
            aq1[j] = f2bf(f2[j] * 0.125f); aq1[4 + j] = f2bf(f3[j] * 0.125f);
        }
    }
    int qg[4], fs[4], fe[4];
    #pragma unroll
    for (int r = 0; r < 4; ++r) {
        qg[r] = qbase + quad * 4 + r; fs[r] = fstarts[qg[r]]; fe[r] = fends[qg[r]];
    }
    floatx4 Oc[4];
    #pragma unroll
    for (int c = 0; c < 4; ++c) Oc[c] = (floatx4){0.f, 0.f, 0.f, 0.f};
    float m_i[4] = {-1e30f, -1e30f, -1e30f, -1e30f};
    float l_i[4] = {0.f, 0.f, 0.f, 0.f};

    for (int kt = 0; kt < S_LEN / 64; ++kt) {
        const int kvbase = kt * 64;
        __syncthreads();
        {
            const int kvr = t >> 2, seg = t & 3;
            if (is_bf16) {
                const short8* gk = (const short8*)(Kb16 + (kvbase + kvr) * D_DIM);
                *(short8*)&Ks[kvr][seg * 8] = gk[seg];
                *(short8*)&Ks[kvr][(seg + 4) * 8] = gk[seg + 4];
                const short8* gv = (const short8*)(Vb16 + (kvbase + kvr) * D_DIM);
                short8 v0 = gv[seg], v1 = gv[seg + 4];
                #pragma unroll
                for (int j = 0; j < 8; ++j) {
                    Vts[seg * 8 + j][kvr] = v0[j];
                    Vts[32 + seg * 8 + j][kvr] = v1[j];
                }
            } else {
                const floatx4* gk = (const floatx4*)(Kbf + (kvbase + kvr) * D_DIM);
                floatx4 k0 = gk[seg * 2], k1 = gk[seg * 2 + 1];
                floatx4 k2 = gk[8 + seg * 2], k3 = gk[8 + seg * 2 + 1];
                #pragma unroll
                for (int j = 0; j < 4; ++j) {
                    Ks[kvr][seg * 8 + j] = f2bf(k0[j]);
                    Ks[kvr][seg * 8 + 4 + j] = f2bf(k1[j]);
                    Ks[kvr][32 + seg * 8 + j] = f2bf(k2[j]);
                    Ks[kvr][32 + seg * 8 + 4 + j] = f2bf(k3[j]);
                }
                const floatx4* gv = (const floatx4*)(Vbf + (kvbase + kvr) * D_DIM);
                floatx4 v0 = gv[seg * 2], v1 = gv[seg * 2 + 1];
                floatx4 v2 = gv[8 + seg * 2], v3 = gv[8 + seg * 2 + 1];
                #pragma unroll
                for (int j = 0; j < 4; ++j) {
                    Vts[seg * 8 + j][kvr] = f2bf(v0[j]);
                    Vts[seg * 8 + 4 + j][kvr] = f2bf(v1[j]);
                    Vts[32 + seg * 8 + j][kvr] = f2bf(v2[j]);
                    Vts[32 + seg * 8 + 4 + j][kvr] = f2bf(v3[j]);
                }
            }
            if (t < 64) {
                int kg = kvbase + t;
                padv[t] = (kg < pad_ends[b * S_LEN + kg]) ? 1 : 0;
            }
        }
        __syncthreads();
        floatx4 sc[4];
        #pragma unroll
        for (int f = 0; f < 4; ++f) {
            short8 b0 = *(const short8*)&Ks[f * 16 + lane16][quad * 8];
            short8 b1 = *(const short8*)&Ks[f * 16 + lane16][32 + quad * 8];
            floatx4 c = (floatx4){0.f, 0.f, 0.f, 0.f};
            c = __builtin_amdgcn_mfma_f32_16x16x32_bf16(aq0, b0, c, 0, 0, 0);
            c = __builtin_amdgcn_mfma_f32_16x16x32_bf16(aq1, b1, c, 0, 0, 0);
            sc[f] = c;
        }
        int col[4], cpad[4];
        #pragma unroll
        for (int f = 0; f < 4; ++f) {
            col[f] = kvbase + f * 16 + lane16;
            cpad[f] = padv[f * 16 + lane16];
        }
        if (cls == 0) {
            #pragma unroll
            for (int r = 0; r < 4; ++r) {
                const int q = qg[r];
                #pragma unroll
                for (int f = 0; f < 4; ++f) {
                    const int k = col[f];
                    bool causal = (!cpad[f]) && (q >= k);
                    bool full = (k >= fs[r]) && (k < fe[r]);
                    bool m = (q == k) != (causal || full);
                    sc[f][r] = m ? sc[f][r] : -1e30f;
                }
            }
        } else if (cls == 1) {
            #pragma unroll
            for (int r = 0; r < 4; ++r) {
                const int q = qg[r];
                #pragma unroll
                for (int f = 0; f < 4; ++f)
                    sc[f][r] = (q >= col[f]) ? sc[f][r] : -1e30f;
            }
        } else {
            #pragma unroll
            for (int r = 0; r < 4; ++r) {
                const int q = qg[r];
                #pragma unroll
                for (int f = 0; f < 4; ++f) {
                    bool m = (q >= col[f]) || (col[f] <= NUM_CLIP_P3);
                    sc[f][r] = m ? sc[f][r] : -1e30f;
                }
            }
        }
        #pragma unroll
        for (int r = 0; r < 4; ++r) {
            float rmax = fmaxf(fmaxf(sc[0][r], sc[1][r]), fmaxf(sc[2][r], sc[3][r]));
            #pragma unroll
            for (int off = 1; off < 16; off <<= 1)
                rmax = fmaxf(rmax, __shfl_xor(rmax, off, 64));
            float mnew = fmaxf(m_i[r], rmax);
            float alpha = __expf(m_i[r] - mnew);
            m_i[r] = mnew;
            float psum = 0.f;
            #pragma unroll
            for (int f = 0; f < 4; ++f) {
                float p = __expf(sc[f][r] - mnew);
                sc[f][r] = p; psum += p;
            }
            #pragma unroll
            for (int off = 1; off < 16; off <<= 1)
                psum += __shfl_xor(psum, off, 64);
            l_i[r] = l_i[r] * alpha + psum;
            Oc[0][r] *= alpha; Oc[1][r] *= alpha; Oc[2][r] *= alpha; Oc[3][r] *= alpha;
        }
        #pragma unroll
        for (int r = 0; r < 4; ++r)
            #pragma unroll
            for (int f = 0; f < 4; ++f)
                Ps[wq][quad * 4 + r][f * 16 + lane16] = f2bf(sc[f][r]);
        __syncthreads();
        short8 a0 = *(const short8*)&Ps[wq][lane16][quad * 8];
        short8 a1 = *(const short8*)&Ps[wq][lane16][32 + quad * 8];
        #pragma unroll
        for (int c = 0; c < 4; ++c) {
            short8 b0 = *(const short8*)&Vts[c * 16 + lane16][quad * 8];
            short8 b1 = *(const short8*)&Vts[c * 16 + lane16][32 + quad * 8];
            Oc[c] = __builtin_amdgcn_mfma_f32_16x16x32_bf16(a0, b0, Oc[c], 0, 0, 0);
            Oc[c] = __builtin_amdgcn_mfma_f32_16x16x32_bf16(a1, b1, Oc[c], 0, 0, 0);
        }
    }
    float* ob = Out + ((long long)bh * S_LEN + qbase) * D_DIM;
    #pragma unroll
    for (int r = 0; r < 4; ++r) {
        float inv = 1.0f / l_i[r];
        #pragma unroll
        for (int c = 0; c < 4; ++c)
            ob[(quad * 4 + r) * D_DIM + c * 16 + lane16] = Oc[c][r] * inv;
    }
}

extern "C" void kernel_launch(void* const* d_in, const int* in_sizes, int n_in,
                              void* d_out, int out_size, void* d_ws, size_t ws_size,
                              hipStream_t stream) {
    const void* Q = d_in[0];
    const void* K = d_in[1];
    const void* V = d_in[2];
    const int* pad_ends = (const int*)d_in[3];
    const int* fstarts  = (const int*)d_in[4];
    const int* fends    = (const int*)d_in[5];
    float* Out = (float*)d_out;

    const size_t kv_bytes = (size_t)KV_ELEMS * 2;           // 12.58 MB each
    const size_t need = 2 * kv_bytes + 16;

    if (ws_size >= need) {
        short* Kw  = (short*)d_ws;
        short* Vtw = Kw + KV_ELEMS;
        int* flags = (int*)((char*)d_ws + 2 * kv_bytes);
        detect_layout<<<1, 64, 0, stream>>>((const unsigned int*)Q, flags);
        preprocess_kv<<<dim3(16, 96, 2), 256, 0, stream>>>(K, V, flags, Kw, Vtw);
        omni_attn_main<<<1536, 256, 0, stream>>>(Q, pad_ends, fstarts, fends,
                                                 flags, Kw, Vtw, Out);
    } else {
        int* flags = (int*)d_ws;
        detect_layout<<<1, 64, 0, stream>>>((const unsigned int*)Q, flags);
        dim3 grid(S_LEN / 64, H_NUM, B_NUM);
        omni_attn_fallback<<<grid, 256, 0, stream>>>(Q, K, V, pad_ends, fstarts,
                                                     fends, flags, Out);
    }
}